// Round 1
// baseline (102.358 us; speedup 1.0000x reference)
//
#include <hip/hip_runtime.h>
#include <stdint.h>

#define M_NODES 4001
#define NW 63            // ceil(4001/64) bitmask words per row
#define DIM 128
#define THRESH 0.04f
#define CAP 64           // neighbor cap (P(deg>64) ~ 0 for Poisson(20); count phase always used 64)
#define SENTINEL 4095    // bit 4095 never set (word 63 == 0)
#define G 4              // spatially-grouped nodes per fv2 block
#define MAXJ2 768        // cap on |union of G M2 rows| (mean ~110)
#define ADJ_RG 16
#define ADJ_BLOCKS (ADJ_RG * NW)                   // 1008
#define FV0_BLOCKS ((M_NODES * DIM + 255) / 256)   // 2001
#define SORT_BLOCK (ADJ_BLOCKS + FV0_BLOCKS)
#define FV2_BLOCKS ((M_NODES + G - 1) / G)         // 1001

typedef unsigned short u16;

// bijective XCD-chunk swizzle (m204): each XCD gets a contiguous chunk of the
// spatially-sorted block order -> per-XCD L2 working set is a small spatial blob.
__device__ __forceinline__ int xcd_swz(int b, int n) {
    int q = n >> 3, r = n & 7, x = b & 7, o = b >> 3;
    return (x < r ? x * (q + 1) : r * (q + 1) + (x - r) * q) + o;
}

// 6-step inclusive shfl scan over 64 lanes.
__device__ __forceinline__ int wave64_incl_scan(int v, int lane) {
#pragma unroll
    for (int d = 1; d < 64; d <<= 1) {
        int n = __shfl_up(v, d, 64);
        if (lane >= d) v += n;
    }
    return v;
}

// ---------- fused fv0 + adjacency + spatial sort ----------
// blocks [0, ADJ_BLOCKS): adjacency bitmask tile. Predicate bit-matches numpy.
// blocks [ADJ_BLOCKS, SORT_BLOCK): fv0 = relu([loc,td] @ W0^T + b).
// block SORT_BLOCK: Morton counting sort of node indices into perm[] (self-contained).
__global__ void prep_kernel(const float* __restrict__ node_loc,
                            const float* __restrict__ td,
                            const float* __restrict__ depot,
                            const float* __restrict__ W0w,
                            const float* __restrict__ W0b,
                            uint64_t* __restrict__ A,
                            float* __restrict__ fv0,
                            int* __restrict__ perm) {
    int tid = threadIdx.x;
    if (blockIdx.x < ADJ_BLOCKS) {
        __shared__ float2 cand[64];
        int rg = blockIdx.x & (ADJ_RG - 1);
        int w  = blockIdx.x >> 4;          // 0..62
        if (tid < 64) {
            int j = w * 64 + tid;
            float2 c;
            if (j == 0) { c.x = depot[0]; c.y = depot[1]; }
            else if (j < M_NODES) { c.x = node_loc[(j - 1) * 2]; c.y = node_loc[(j - 1) * 2 + 1]; }
            else { c.x = 1e9f; c.y = 1e9f; }
            cand[tid] = c;
        }
        int i = rg * 256 + tid;
        float xi = 0.f, yi = 0.f;
        if (i == 0) { xi = depot[0]; yi = depot[1]; }
        else if (i < M_NODES) { xi = node_loc[(i - 1) * 2]; yi = node_loc[(i - 1) * 2 + 1]; }
        __syncthreads();
        uint64_t m = 0;
#pragma unroll
        for (int b = 0; b < 64; ++b) {
#pragma clang fp contract(off)
            float dx = xi - cand[b].x;
            float dy = yi - cand[b].y;
            float xx = dx * dx;
            float yy = dy * dy;
            float d2 = xx + yy;
            if (sqrtf(d2) <= THRESH) m |= (1ull << b);
        }
        if (i < M_NODES) A[(size_t)i * NW + w] = m;
    } else if (blockIdx.x < SORT_BLOCK) {
        int idx = (blockIdx.x - ADJ_BLOCKS) * 256 + tid;
        if (idx < M_NODES * DIM) {
            int i = idx >> 7;
            int d = idx & (DIM - 1);
            float lx, ly, t;
            if (i == 0) { lx = depot[0]; ly = depot[1]; t = 0.f; }
            else { lx = node_loc[(i - 1) * 2]; ly = node_loc[(i - 1) * 2 + 1]; t = td[i - 1]; }
            float v = fmaf(lx, W0w[d * 3 + 0], fmaf(ly, W0w[d * 3 + 1], fmaf(t, W0w[d * 3 + 2], W0b[d])));
            fv0[idx] = v > 0.f ? v : 0.f;
        }
    } else {
        // Morton counting sort: 16x16 cells (~15.6 nodes/cell), 256 cells == 256 threads.
        __shared__ int hist[256];
        __shared__ int wtot[4];
        __shared__ int coff[256];
        int lane = tid & 63, w = tid >> 6;
        hist[tid] = 0;
        __syncthreads();
        int mcs[16];
#pragma unroll
        for (int k = 0; k < 16; ++k) {
            int i = k * 256 + tid;
            int mc = -1;
            if (i < M_NODES) {
                float x, y;
                if (i == 0) { x = depot[0]; y = depot[1]; }
                else { x = node_loc[(i - 1) * 2]; y = node_loc[(i - 1) * 2 + 1]; }
                int cx = (int)(x * 16.f); cx = cx < 0 ? 0 : (cx > 15 ? 15 : cx);
                int cy = (int)(y * 16.f); cy = cy < 0 ? 0 : (cy > 15 ? 15 : cy);
                mc = 0;
#pragma unroll
                for (int bb = 0; bb < 4; ++bb)
                    mc |= (((cx >> bb) & 1) << (2 * bb)) | (((cy >> bb) & 1) << (2 * bb + 1));
                atomicAdd(&hist[mc], 1);
            }
            mcs[k] = mc;
        }
        __syncthreads();
        int v = hist[tid];
        int incl = wave64_incl_scan(v, lane);
        if (lane == 63) wtot[w] = incl;
        __syncthreads();
        int add = 0;
#pragma unroll
        for (int ww = 0; ww < 3; ++ww) if (ww < w) add += wtot[ww];
        coff[tid] = add + incl - v;        // exclusive cell start
        __syncthreads();
#pragma unroll
        for (int k = 0; k < 16; ++k) {
            if (mcs[k] >= 0) {
                int pos = atomicAdd(&coff[mcs[k]], 1);
                perm[pos] = k * 256 + tid;
            }
        }
    }
}

// ---------- fused CSR build + fv_1 ----------
// Blocks walk perm[] with XCD-chunk swizzle so the fv0 gather is L2-resident.
// nbr16: u16 rows of 64 entries (128B), sentinel-padded.
__global__ void fv1csr_kernel(const uint64_t* __restrict__ A,
                              const float* __restrict__ fv0,
                              const int* __restrict__ perm,
                              u16* __restrict__ nbr16, int* __restrict__ deg,
                              float* __restrict__ fv1) {
    __shared__ int slist[CAP];
    __shared__ float4 part[8][32];
    __shared__ int snn;
    int tid = threadIdx.x;
    int i = perm[xcd_swz(blockIdx.x, M_NODES)];
    if (tid < 64) {
        uint64_t m = (tid < NW) ? A[(size_t)i * NW + tid] : 0ull;
        int c = __popcll(m);
        int incl = wave64_incl_scan(c, tid);
        int oo = incl - c;
        int base = tid * 64;
        while (m) {
            int b = __builtin_ctzll(m);
            if (oo < CAP) { slist[oo] = base + b; nbr16[(size_t)i * CAP + oo] = (u16)(base + b); }
            ++oo;
            m &= m - 1;
        }
        int tot = __shfl(incl, 63, 64);
        if (tot > CAP) tot = CAP;
        if (tid == 0) { deg[i] = tot; snn = tot; }
        int s = tot + tid;                       // sentinel-pad slots [tot,64)
        if (s < CAP) nbr16[(size_t)i * CAP + s] = (u16)SENTINEL;
    }
    __syncthreads();
    int n1 = snn;
    int lane32 = tid & 31, g = tid >> 5;
    const float4* fv0v = (const float4*)fv0;     // row = 32 float4
    float4 acc = {0.f, 0.f, 0.f, 0.f};
    for (int l = g; l < n1; l += 8) {
        float4 v = fv0v[(size_t)slist[l] * 32 + lane32];
        acc.x += v.x; acc.y += v.y; acc.z += v.z; acc.w += v.w;
    }
    part[g][lane32] = acc;
    __syncthreads();
    if (tid < 32) {
        float4 s = part[0][tid];
#pragma unroll
        for (int gg = 1; gg < 8; ++gg) {
            float4 p = part[gg][tid];
            s.x += p.x; s.y += p.y; s.z += p.z; s.w += p.w;
        }
        ((float4*)fv1)[(size_t)i * 32 + tid] = s;
    }
}

// ---------- fv_2, G=4 spatially-grouped ----------
// Block handles 4 consecutive perm entries (same Morton cell -> overlapping M2).
// Builds 4 M2 bitmask rows (wave g builds row g), enumerates the UNION once with
// a 4-bit per-node membership mask packed into u16 entries (j|gm<<12), then per
// union-j loads nbr16 (128B) + fv1 (512B) ONCE and does 4 gated ballot-counts.
__global__ void fv2_kernel(const uint64_t* __restrict__ A,
                           const int* __restrict__ perm,
                           const u16* __restrict__ nbr16, const int* __restrict__ deg,
                           const float* __restrict__ fv1, float* __restrict__ out) {
    __shared__ uint64_t m2sep[G][64];
    __shared__ u16 list1s[G][CAP];
    __shared__ u16 list2[MAXJ2];
    __shared__ float2 wacc[4][G][64];
    __shared__ int sidx[G], sdeg[G];
    __shared__ int snn2;

    int tid = threadIdx.x, lane = tid & 63, wave = tid >> 6;
    int vb = xcd_swz(blockIdx.x, FV2_BLOCKS);
    if (tid < G) {
        int idx4 = vb * G + tid;
        int ii = (idx4 < M_NODES) ? perm[idx4] : -1;
        sidx[tid] = ii;
        sdeg[tid] = (ii >= 0) ? deg[ii] : 0;
    }
    __syncthreads();

    // wave g stages + builds its own M2 row (no barrier needed between stage/use).
    int myi = sidx[wave];
    list1s[wave][lane] = (myi >= 0) ? nbr16[(size_t)myi * CAP + lane] : (u16)SENTINEL;
    int n1 = sdeg[wave];
    uint64_t o = 0;
    {
        int l = 0;
        for (; l + 3 < n1; l += 4) {
            int j0 = list1s[wave][l],     j1 = list1s[wave][l + 1];
            int j2 = list1s[wave][l + 2], j3 = list1s[wave][l + 3];
            if (lane < NW)
                o |= A[(size_t)j0 * NW + lane] | A[(size_t)j1 * NW + lane]
                   | A[(size_t)j2 * NW + lane] | A[(size_t)j3 * NW + lane];
        }
        for (; l < n1; ++l) {
            int j0 = list1s[wave][l];
            if (lane < NW) o |= A[(size_t)j0 * NW + lane];
        }
    }
    m2sep[wave][lane] = o;     // lane 63 writes 0 (never loaded) -> sentinel-safe
    __syncthreads();

    // wave 0: union + 4-bit membership mask, deterministic enumerate.
    if (tid < 64) {
        uint64_t m0 = m2sep[0][tid], m1 = m2sep[1][tid];
        uint64_t mm2 = m2sep[2][tid], m3 = m2sep[3][tid];
        uint64_t mu = m0 | m1 | mm2 | m3;
        int c = __popcll(mu);
        int incl = wave64_incl_scan(c, tid);
        int oo = incl - c;
        int base = tid * 64;
        while (mu) {
            int b = __builtin_ctzll(mu);
            int gm = (int)((m0 >> b) & 1) | ((int)((m1 >> b) & 1) << 1)
                   | ((int)((mm2 >> b) & 1) << 2) | ((int)((m3 >> b) & 1) << 3);
            if (oo < MAXJ2) list2[oo] = (u16)((base + b) | (gm << 12));
            ++oo;
            mu &= mu - 1;
        }
        if (tid == 63) snn2 = incl < MAXJ2 ? incl : MAXJ2;
    }
    __syncthreads();
    int n2u = snn2;

    // main loop: wave per union-j (l == wave mod 4), unroll-2; shared loads, 4 gated counts.
    const float2* fv1v = (const float2*)fv1;     // row = 64 float2
    float2 a0 = {0.f, 0.f}, a1 = {0.f, 0.f}, a2 = {0.f, 0.f}, a3 = {0.f, 0.f};
    int l = wave;
    for (; l + 4 < n2u; l += 8) {
        int e0 = list2[l], e1 = list2[l + 4];
        int j0 = e0 & 4095, j1 = e1 & 4095;
        int u0 = nbr16[(size_t)j0 * CAP + lane];         // 128B coalesced
        int u1 = nbr16[(size_t)j1 * CAP + lane];
        float2 r0 = fv1v[(size_t)j0 * 64 + lane];        // 512B coalesced
        float2 r1 = fv1v[(size_t)j1 * 64 + lane];
        uint64_t bm0 = 1ull << (u0 & 63); int w0 = u0 >> 6;
        uint64_t bm1 = 1ull << (u1 & 63); int w1 = u1 >> 6;
        int c00 = __popcll(__ballot((m2sep[0][w0] & bm0) != 0));
        int c10 = __popcll(__ballot((m2sep[1][w0] & bm0) != 0));
        int c20 = __popcll(__ballot((m2sep[2][w0] & bm0) != 0));
        int c30 = __popcll(__ballot((m2sep[3][w0] & bm0) != 0));
        int c01 = __popcll(__ballot((m2sep[0][w1] & bm1) != 0));
        int c11 = __popcll(__ballot((m2sep[1][w1] & bm1) != 0));
        int c21 = __popcll(__ballot((m2sep[2][w1] & bm1) != 0));
        int c31 = __popcll(__ballot((m2sep[3][w1] & bm1) != 0));
        float f00 = (e0 & (1 << 12)) ? (float)c00 : 0.f;
        float f10 = (e0 & (2 << 12)) ? (float)c10 : 0.f;
        float f20 = (e0 & (4 << 12)) ? (float)c20 : 0.f;
        float f30 = (e0 & (8 << 12)) ? (float)c30 : 0.f;
        float f01 = (e1 & (1 << 12)) ? (float)c01 : 0.f;
        float f11 = (e1 & (2 << 12)) ? (float)c11 : 0.f;
        float f21 = (e1 & (4 << 12)) ? (float)c21 : 0.f;
        float f31 = (e1 & (8 << 12)) ? (float)c31 : 0.f;
        a0.x = fmaf(f00, r0.x, a0.x); a0.y = fmaf(f00, r0.y, a0.y);
        a1.x = fmaf(f10, r0.x, a1.x); a1.y = fmaf(f10, r0.y, a1.y);
        a2.x = fmaf(f20, r0.x, a2.x); a2.y = fmaf(f20, r0.y, a2.y);
        a3.x = fmaf(f30, r0.x, a3.x); a3.y = fmaf(f30, r0.y, a3.y);
        a0.x = fmaf(f01, r1.x, a0.x); a0.y = fmaf(f01, r1.y, a0.y);
        a1.x = fmaf(f11, r1.x, a1.x); a1.y = fmaf(f11, r1.y, a1.y);
        a2.x = fmaf(f21, r1.x, a2.x); a2.y = fmaf(f21, r1.y, a2.y);
        a3.x = fmaf(f31, r1.x, a3.x); a3.y = fmaf(f31, r1.y, a3.y);
    }
    for (; l < n2u; l += 4) {
        int e0 = list2[l];
        int j0 = e0 & 4095;
        int u0 = nbr16[(size_t)j0 * CAP + lane];
        float2 r0 = fv1v[(size_t)j0 * 64 + lane];
        uint64_t bm0 = 1ull << (u0 & 63); int w0 = u0 >> 6;
        int c00 = __popcll(__ballot((m2sep[0][w0] & bm0) != 0));
        int c10 = __popcll(__ballot((m2sep[1][w0] & bm0) != 0));
        int c20 = __popcll(__ballot((m2sep[2][w0] & bm0) != 0));
        int c30 = __popcll(__ballot((m2sep[3][w0] & bm0) != 0));
        float f00 = (e0 & (1 << 12)) ? (float)c00 : 0.f;
        float f10 = (e0 & (2 << 12)) ? (float)c10 : 0.f;
        float f20 = (e0 & (4 << 12)) ? (float)c20 : 0.f;
        float f30 = (e0 & (8 << 12)) ? (float)c30 : 0.f;
        a0.x = fmaf(f00, r0.x, a0.x); a0.y = fmaf(f00, r0.y, a0.y);
        a1.x = fmaf(f10, r0.x, a1.x); a1.y = fmaf(f10, r0.y, a1.y);
        a2.x = fmaf(f20, r0.x, a2.x); a2.y = fmaf(f20, r0.y, a2.y);
        a3.x = fmaf(f30, r0.x, a3.x); a3.y = fmaf(f30, r0.y, a3.y);
    }

    // cross-wave reduce: wave w dumps its 4 partials; wave g sums column g, stores row i_g.
    wacc[wave][0][lane] = a0; wacc[wave][1][lane] = a1;
    wacc[wave][2][lane] = a2; wacc[wave][3][lane] = a3;
    __syncthreads();
    if (myi >= 0) {
        float2 s  = wacc[0][wave][lane];
        float2 p1 = wacc[1][wave][lane];
        float2 p2 = wacc[2][wave][lane];
        float2 p3 = wacc[3][wave][lane];
        s.x = ((s.x + p1.x) + p2.x) + p3.x;
        s.y = ((s.y + p1.y) + p2.y) + p3.y;
        ((float2*)out)[(size_t)myi * 64 + lane] = s;   // coalesced 512B
    }
}

extern "C" void kernel_launch(void* const* d_in, const int* in_sizes, int n_in,
                              void* d_out, int out_size, void* d_ws, size_t ws_size,
                              hipStream_t stream) {
    const float* node_loc = (const float*)d_in[0];  // [4000,2]
    const float* td       = (const float*)d_in[1];  // [4000,1]
    const float* depot    = (const float*)d_in[2];  // [1,2]
    const float* W0w      = (const float*)d_in[3];  // [128,3]
    const float* W0b      = (const float*)d_in[4];  // [128]
    float* out = (float*)d_out;                     // [4001,128]

    char* base = (char*)d_ws;
    size_t off = 0;
    auto carve = [&](size_t bytes) {
        char* p = base + off;
        off = (off + bytes + 511) & ~(size_t)511;
        return p;
    };
    uint64_t* A    = (uint64_t*)carve((size_t)M_NODES * NW * sizeof(uint64_t));  // ~2.0 MB
    float*    fv0  = (float*)   carve((size_t)M_NODES * DIM * sizeof(float));    // ~2.0 MB
    float*    fv1  = (float*)   carve((size_t)M_NODES * DIM * sizeof(float));    // ~2.0 MB
    u16*      nbr16= (u16*)     carve((size_t)M_NODES * CAP * sizeof(u16));      // ~0.5 MB
    int*      deg  = (int*)     carve((size_t)M_NODES * sizeof(int));            // 16 KB
    int*      perm = (int*)     carve((size_t)M_NODES * sizeof(int));            // 16 KB

    prep_kernel<<<SORT_BLOCK + 1, 256, 0, stream>>>(node_loc, td, depot,
                                                    W0w, W0b, A, fv0, perm);
    fv1csr_kernel<<<M_NODES, 256, 0, stream>>>(A, fv0, perm, nbr16, deg, fv1);
    fv2_kernel<<<FV2_BLOCKS, 256, 0, stream>>>(A, perm, nbr16, deg, fv1, out);
}